// Round 2
// baseline (313.620 us; speedup 1.0000x reference)
//
#include <hip/hip_runtime.h>
#include <hip/hip_bf16.h>
#include <hip/hip_cooperative_groups.h>

namespace cg = cooperative_groups;

// B=16, S=8192, D=128, H=512, N_ROT=3
// Single cooperative kernel, phases separated by grid.sync():
//  P0 pool partials   x -> PART[1024][128]
//  P1 reduce+MLP1     PART -> h[16][512]           (16 blocks)
//  P2 G = h@W2^T+b2   MFMA, W2-bound -> GT[j][b]
//  P3 expm per (b,rot): g in global scratch (f32, GA layout), s-iterates bf16 in LDS
//  P4 compose sR = (I+s0)(I+s1)(I+s2)-I -> SRT bf16 [e][d]
//  P5 out = x + x*sR  (MFMA, memory-bound)
// Fallback: the proven 6-kernel pipeline if cooperative launch fails.

typedef float  f4  __attribute__((ext_vector_type(4)));
typedef __bf16 bf8 __attribute__((ext_vector_type(8)));
typedef short  s8  __attribute__((ext_vector_type(8)));
typedef short  sh4 __attribute__((ext_vector_type(4)));

__device__ __forceinline__ short bf16s(float f) {
    unsigned u = __builtin_bit_cast(unsigned, f);
    u += 0x7FFFu + ((u >> 16) & 1u);   // RNE
    return (short)(u >> 16);
}

__device__ __forceinline__ s8 pack8(f4 lo, f4 hi) {
    s8 r;
    r[0] = bf16s(lo.x); r[1] = bf16s(lo.y); r[2] = bf16s(lo.z); r[3] = bf16s(lo.w);
    r[4] = bf16s(hi.x); r[5] = bf16s(hi.y); r[6] = bf16s(hi.z); r[7] = bf16s(hi.w);
    return r;
}

__device__ __forceinline__ f4 mfma_bf16(s8 a, s8 b, f4 c) {
    return __builtin_amdgcn_mfma_f32_16x16x32_bf16(
        __builtin_bit_cast(bf8, a), __builtin_bit_cast(bf8, b), c, 0, 0, 0);
}

struct P5S { float x32[64][132]; short xb[64][136]; };   // 51.2 KB
union ShU {
    P5S  a;
    short st[128][136];                                   // 34.8 KB
    f4   red[8][32];
    float pooled[128];
};

// ============================ MEGA (cooperative) ============================
__global__ __launch_bounds__(256) void mega(
        const float* __restrict__ x,  const float* __restrict__ W1,
        const float* __restrict__ b1, const float* __restrict__ W2,
        const float* __restrict__ b2, float* __restrict__ out,
        float* __restrict__ PART, float* __restrict__ H,
        float* __restrict__ GT,   float* __restrict__ GGA,
        float* __restrict__ S_RM, float* __restrict__ S_TR,
        float* __restrict__ ST_RM, float* __restrict__ ST_TR,
        short* __restrict__ SRT) {
    __shared__ ShU sh;
    cg::grid_group gg = cg::this_grid();
    const int tid  = threadIdx.x;
    const int lane = tid & 63, wave = tid >> 6;
    const int G    = gridDim.x;

    // ---------------- P0: pool partials ----------------
    {
        int laned = (tid & 31) * 4;
        int rowg  = tid >> 5;                 // 0..7
        for (int u = blockIdx.x; u < 1024; u += G) {
            __syncthreads();
            int b = u >> 6, chunk = u & 63;
            const float* xb = x + ((size_t)b * 8192 + (size_t)chunk * 128) * 128;
            f4 acc = {0.f, 0.f, 0.f, 0.f};
            for (int r = rowg; r < 128; r += 8)
                acc += *(const f4*)(xb + (size_t)r * 128 + laned);
            sh.red[rowg][tid & 31] = acc;
            __syncthreads();
            if (tid < 32) {
                f4 s = sh.red[0][tid];
                #pragma unroll
                for (int g2 = 1; g2 < 8; g2++) s += sh.red[g2][tid];
                *(f4*)(PART + (size_t)u * 128 + tid * 4) = s;
            }
        }
    }
    gg.sync();

    // ---------------- P1: reduce + MLP1 + gelu ----------------
    for (int b = blockIdx.x; b < 16; b += G) {
        __syncthreads();
        if (tid < 128) {
            float s = 0.f;
            for (int c = 0; c < 64; c++)
                s += PART[((size_t)b * 64 + c) * 128 + tid];
            sh.pooled[tid] = s * (1.0f / 8192.0f);
        }
        __syncthreads();
        for (int j = tid; j < 512; j += 256) {
            const float* w = W1 + (size_t)j * 128;
            float z = b1[j];
            #pragma unroll 4
            for (int k = 0; k < 128; k += 4) {
                f4 wv = *(const f4*)(w + k);
                z += wv.x * sh.pooled[k] + wv.y * sh.pooled[k + 1]
                   + wv.z * sh.pooled[k + 2] + wv.w * sh.pooled[k + 3];
            }
            H[(size_t)b * 512 + j] = 0.5f * z * (1.0f + erff(z * 0.70710678118654752f));
        }
        __syncthreads();
    }
    gg.sync();

    // ---------------- P2: G = h @ W2^T + b2 -> GT[j][b] ----------------
    {
        int cr = lane & 15, q = lane >> 4;
        for (int nt = blockIdx.x * 4 + wave; nt < 3072; nt += G * 4) {
            int j = nt * 16 + cr;
            const float* hA = H  + (size_t)cr * 512 + 8 * q;
            const float* wB = W2 + (size_t)j  * 512 + 8 * q;
            f4 acc = {0.f, 0.f, 0.f, 0.f};
            #pragma unroll
            for (int kc = 0; kc < 16; kc++) {
                f4 a0  = *(const f4*)(hA + kc * 32);
                f4 a1  = *(const f4*)(hA + kc * 32 + 4);
                f4 b0  = *(const f4*)(wB + kc * 32);
                f4 b1v = *(const f4*)(wB + kc * 32 + 4);
                acc = mfma_bf16(pack8(a0, a1), pack8(b0, b1v), acc);
            }
            f4 o = acc + b2[j];
            *(f4*)(GT + (size_t)j * 16 + 4 * q) = o;
        }
    }
    gg.sync();

    // ---------------- P3: s = exp(g)-I per (b,rot) ----------------
    for (int blk = blockIdx.x; blk < 48; blk += G) {
        __syncthreads();
        int bb = blk / 3, rot = blk - bb * 3;
        const float* Gb = GT + (size_t)rot * 262144 + bb;
        float* ga = GGA + (size_t)blk * 16384;        // ga[r][c] = g[c][r]
        for (int idx = tid; idx < 16384; idx += 256) {
            int r = idx >> 7, c = idx & 127;
            float Gcr = Gb[(size_t)(c * 128 + r) * 16];
            float Grc = Gb[(size_t)(r * 128 + c) * 16];
            float v = 0.5f * (Gcr - Grc);             // g[c][r]
            ga[idx] = v;
            sh.st[r][c] = bf16s(v * 0.125f);          // s7 = g/8 (st[n][k]=s[k][n])
        }
        __syncthreads();
        int cr = lane & 15, q = lane >> 4;
        int mh = (wave >> 1) * 64, nh = (wave & 1) * 64;
        s8 afr[4][4];
        #pragma unroll
        for (int mt = 0; mt < 4; mt++) {
            int m = mh + mt * 16 + cr;
            #pragma unroll
            for (int kc = 0; kc < 4; kc++) {
                int k0 = kc * 32 + 8 * q;
                f4 lo = *(const f4*)(ga + (size_t)m * 128 + k0);
                f4 hi = *(const f4*)(ga + (size_t)m * 128 + k0 + 4);
                afr[mt][kc] = pack8(-lo, -hi);        // g[m][k] = -ga[m][k]
            }
        }
        size_t soff = (size_t)blk * 16384;
        for (int s = 0; s < 7; s++) {
            const float inv = 1.0f / (float)(7 - s);
            f4 acc[4][4] = {};
            #pragma unroll
            for (int ntl = 0; ntl < 4; ntl++) {
                int n = nh + ntl * 16 + cr;
                #pragma unroll
                for (int kc = 0; kc < 4; kc++) {
                    s8 bfrag = *(const s8*)&sh.st[n][kc * 32 + 8 * q];
                    #pragma unroll
                    for (int mt = 0; mt < 4; mt++)
                        acc[mt][ntl] = mfma_bf16(afr[mt][kc], bfrag, acc[mt][ntl]);
                }
            }
            __syncthreads();
            #pragma unroll
            for (int mt = 0; mt < 4; mt++) {
                int m0 = mh + mt * 16 + 4 * q;
                #pragma unroll
                for (int ntl = 0; ntl < 4; ntl++) {
                    int n = nh + ntl * 16 + cr;
                    f4 gv = *(const f4*)(ga + (size_t)n * 128 + m0);   // g[m0..+3][n]
                    f4 val = (acc[mt][ntl] + gv) * inv;
                    if (s < 6) {
                        sh4 w;
                        w[0] = bf16s(val.x); w[1] = bf16s(val.y);
                        w[2] = bf16s(val.z); w[3] = bf16s(val.w);
                        *(sh4*)&sh.st[n][m0] = w;
                    } else {
                        *(f4*)(S_TR + soff + (size_t)n * 128 + m0) = val;
                        S_RM[soff + (size_t)(m0 + 0) * 128 + n] = val.x;
                        S_RM[soff + (size_t)(m0 + 1) * 128 + n] = val.y;
                        S_RM[soff + (size_t)(m0 + 2) * 128 + n] = val.z;
                        S_RM[soff + (size_t)(m0 + 3) * 128 + n] = val.w;
                    }
                }
            }
            if (s < 6) __syncthreads();
        }
    }
    gg.sync();

    // ---------------- P4: compose -> SRT ----------------
    for (int bb = blockIdx.x; bb < 16; bb += G) {
        int cr = lane & 15, q = lane >> 4;
        int mh = (wave >> 1) * 64, nh = (wave & 1) * 64;
        const size_t o0 = (size_t)(bb * 3 + 0) * 16384;
        const size_t o1 = (size_t)(bb * 3 + 1) * 16384;
        const size_t o2 = (size_t)(bb * 3 + 2) * 16384;
        const size_t oT = (size_t)bb * 16384;
        {   // T = s0 + s1 + s0*s1
            s8 afr[4][4];
            #pragma unroll
            for (int mt = 0; mt < 4; mt++) {
                int m = mh + mt * 16 + cr;
                #pragma unroll
                for (int kc = 0; kc < 4; kc++) {
                    int k0 = kc * 32 + 8 * q;
                    f4 lo = *(const f4*)(S_RM + o0 + (size_t)m * 128 + k0);
                    f4 hi = *(const f4*)(S_RM + o0 + (size_t)m * 128 + k0 + 4);
                    afr[mt][kc] = pack8(lo, hi);
                }
            }
            f4 acc[4][4] = {};
            #pragma unroll
            for (int ntl = 0; ntl < 4; ntl++) {
                int n = nh + ntl * 16 + cr;
                #pragma unroll
                for (int kc = 0; kc < 4; kc++) {
                    int k0 = kc * 32 + 8 * q;
                    f4 lo = *(const f4*)(S_TR + o1 + (size_t)n * 128 + k0);
                    f4 hi = *(const f4*)(S_TR + o1 + (size_t)n * 128 + k0 + 4);
                    s8 bfrag = pack8(lo, hi);
                    #pragma unroll
                    for (int mt = 0; mt < 4; mt++)
                        acc[mt][ntl] = mfma_bf16(afr[mt][kc], bfrag, acc[mt][ntl]);
                }
            }
            #pragma unroll
            for (int mt = 0; mt < 4; mt++) {
                int m0 = mh + mt * 16 + 4 * q;
                #pragma unroll
                for (int ntl = 0; ntl < 4; ntl++) {
                    int n = nh + ntl * 16 + cr;
                    f4 a = *(const f4*)(S_TR + o0 + (size_t)n * 128 + m0);
                    f4 c = *(const f4*)(S_TR + o1 + (size_t)n * 128 + m0);
                    f4 val = acc[mt][ntl] + a + c;
                    *(f4*)(ST_TR + oT + (size_t)n * 128 + m0) = val;
                    ST_RM[oT + (size_t)(m0 + 0) * 128 + n] = val.x;
                    ST_RM[oT + (size_t)(m0 + 1) * 128 + n] = val.y;
                    ST_RM[oT + (size_t)(m0 + 2) * 128 + n] = val.z;
                    ST_RM[oT + (size_t)(m0 + 3) * 128 + n] = val.w;
                }
            }
        }
        __syncthreads();
        {   // sR = T + s2 + T*s2
            s8 afr[4][4];
            #pragma unroll
            for (int mt = 0; mt < 4; mt++) {
                int m = mh + mt * 16 + cr;
                #pragma unroll
                for (int kc = 0; kc < 4; kc++) {
                    int k0 = kc * 32 + 8 * q;
                    f4 lo = *(const f4*)(ST_RM + oT + (size_t)m * 128 + k0);
                    f4 hi = *(const f4*)(ST_RM + oT + (size_t)m * 128 + k0 + 4);
                    afr[mt][kc] = pack8(lo, hi);
                }
            }
            f4 acc[4][4] = {};
            #pragma unroll
            for (int ntl = 0; ntl < 4; ntl++) {
                int n = nh + ntl * 16 + cr;
                #pragma unroll
                for (int kc = 0; kc < 4; kc++) {
                    int k0 = kc * 32 + 8 * q;
                    f4 lo = *(const f4*)(S_TR + o2 + (size_t)n * 128 + k0);
                    f4 hi = *(const f4*)(S_TR + o2 + (size_t)n * 128 + k0 + 4);
                    s8 bfrag = pack8(lo, hi);
                    #pragma unroll
                    for (int mt = 0; mt < 4; mt++)
                        acc[mt][ntl] = mfma_bf16(afr[mt][kc], bfrag, acc[mt][ntl]);
                }
            }
            #pragma unroll
            for (int mt = 0; mt < 4; mt++) {
                int m0 = mh + mt * 16 + 4 * q;
                #pragma unroll
                for (int ntl = 0; ntl < 4; ntl++) {
                    int n = nh + ntl * 16 + cr;
                    f4 a = *(const f4*)(ST_TR + oT + (size_t)n * 128 + m0);
                    f4 c = *(const f4*)(S_TR + o2 + (size_t)n * 128 + m0);
                    f4 val = acc[mt][ntl] + a + c;                 // sR[m0..+3][n]
                    sh4 w;
                    w[0] = bf16s(val.x); w[1] = bf16s(val.y);
                    w[2] = bf16s(val.z); w[3] = bf16s(val.w);
                    *(sh4*)(SRT + oT + (size_t)n * 128 + m0) = w;  // SRT[e=n][d]
                }
            }
        }
    }
    gg.sync();

    // ---------------- P5: out = x + x*sR ----------------
    {
        int cr = lane & 15, q = lane >> 4;
        for (int u = blockIdx.x; u < 2048; u += G) {
            __syncthreads();
            int b = u >> 7, tile = u & 127;
            const float* xbase = x   + ((size_t)b * 8192 + (size_t)tile * 64) * 128;
            float*       obase = out + ((size_t)b * 8192 + (size_t)tile * 64) * 128;
            #pragma unroll
            for (int ii = 0; ii < 8; ii++) {
                int flat4 = ii * 256 + tid;
                int row = flat4 >> 5, col = (flat4 & 31) * 4;
                f4 v = *(const f4*)(xbase + (size_t)row * 128 + col);
                *(f4*)&sh.a.x32[row][col] = v;
                sh4 w;
                w[0] = bf16s(v.x); w[1] = bf16s(v.y); w[2] = bf16s(v.z); w[3] = bf16s(v.w);
                *(sh4*)&sh.a.xb[row][col] = w;
            }
            const short* Ab = SRT + (size_t)b * 16384;
            s8 afr[2][4];
            #pragma unroll
            for (int mt = 0; mt < 2; mt++) {
                int e = wave * 32 + mt * 16 + cr;
                #pragma unroll
                for (int kc = 0; kc < 4; kc++)
                    afr[mt][kc] = *(const s8*)(Ab + (size_t)e * 128 + kc * 32 + 8 * q);
            }
            __syncthreads();
            #pragma unroll
            for (int strip = 0; strip < 4; strip++) {
                int srow = strip * 16 + cr;
                f4 acc0 = {0.f,0.f,0.f,0.f}, acc1 = {0.f,0.f,0.f,0.f};
                #pragma unroll
                for (int kc = 0; kc < 4; kc++) {
                    s8 bfrag = *(const s8*)&sh.a.xb[srow][kc * 32 + 8 * q];
                    acc0 = mfma_bf16(afr[0][kc], bfrag, acc0);
                    acc1 = mfma_bf16(afr[1][kc], bfrag, acc1);
                }
                #pragma unroll
                for (int mt = 0; mt < 2; mt++) {
                    int e0 = wave * 32 + mt * 16 + 4 * q;
                    f4 xv = *(const f4*)&sh.a.x32[srow][e0];
                    f4 o = (mt ? acc1 : acc0) + xv;
                    *(f4*)(obase + (size_t)srow * 128 + e0) = o;
                }
            }
        }
    }
}

// ======================= fallback: 6-kernel pipeline =======================
__global__ __launch_bounds__(256) void k1_pool(const float* __restrict__ x,
                                               float* __restrict__ part) {
    int b = blockIdx.x >> 6, chunk = blockIdx.x & 63;
    int laned = (threadIdx.x & 31) * 4, rowg = threadIdx.x >> 5;
    const float* xb = x + ((size_t)b * 8192 + (size_t)chunk * 128) * 128;
    f4 acc = {0.f,0.f,0.f,0.f};
    for (int r = rowg; r < 128; r += 8)
        acc += *(const f4*)(xb + (size_t)r * 128 + laned);
    __shared__ f4 red[8][32];
    red[rowg][threadIdx.x & 31] = acc;
    __syncthreads();
    if (threadIdx.x < 32) {
        f4 s = red[0][threadIdx.x];
        #pragma unroll
        for (int g = 1; g < 8; g++) s += red[g][threadIdx.x];
        *(f4*)(part + ((size_t)b * 64 + chunk) * 128 + threadIdx.x * 4) = s;
    }
}

__global__ __launch_bounds__(512) void k2a_h(const float* __restrict__ part,
                                             const float* __restrict__ W1,
                                             const float* __restrict__ b1,
                                             float* __restrict__ h) {
    int b = blockIdx.x;
    __shared__ float pooled[128];
    if (threadIdx.x < 128) {
        float s = 0.f;
        for (int c = 0; c < 64; c++)
            s += part[((size_t)b * 64 + c) * 128 + threadIdx.x];
        pooled[threadIdx.x] = s * (1.0f / 8192.0f);
    }
    __syncthreads();
    int j = threadIdx.x;
    const float* w = W1 + (size_t)j * 128;
    float z = b1[j];
    #pragma unroll 4
    for (int k = 0; k < 128; k += 4) {
        f4 wv = *(const f4*)(w + k);
        z += wv.x * pooled[k] + wv.y * pooled[k+1] + wv.z * pooled[k+2] + wv.w * pooled[k+3];
    }
    h[(size_t)b * 512 + j] = 0.5f * z * (1.0f + erff(z * 0.70710678118654752f));
}

__global__ __launch_bounds__(256) void k2b_G(const float* __restrict__ h,
                                             const float* __restrict__ W2,
                                             const float* __restrict__ b2,
                                             float* __restrict__ GT) {
    int lane = threadIdx.x & 63, wave = threadIdx.x >> 6;
    int ntile = blockIdx.x * 4 + wave;
    int cr = lane & 15, q = lane >> 4;
    int j = ntile * 16 + cr;
    const float* hA = h + (size_t)cr * 512 + 8 * q;
    const float* wB = W2 + (size_t)j * 512 + 8 * q;
    f4 acc = {0.f,0.f,0.f,0.f};
    #pragma unroll
    for (int kc = 0; kc < 16; kc++) {
        f4 a0 = *(const f4*)(hA + kc * 32);
        f4 a1 = *(const f4*)(hA + kc * 32 + 4);
        f4 b0 = *(const f4*)(wB + kc * 32);
        f4 b1v = *(const f4*)(wB + kc * 32 + 4);
        acc = mfma_bf16(pack8(a0, a1), pack8(b0, b1v), acc);
    }
    f4 o = acc + b2[j];
    *(f4*)(GT + (size_t)j * 16 + 4 * q) = o;
}

__global__ __launch_bounds__(256) void k3_expm(const float* __restrict__ GT,
                                               float* __restrict__ s_rm,
                                               float* __restrict__ s_tr) {
    __shared__ float GA[128][132];
    __shared__ short st[128][136];
    int blk = blockIdx.x;
    int bb = blk / 3, rot = blk % 3;
    const float* Gbase = GT + (size_t)rot * 16384 * 16 + bb;
    for (int idx = threadIdx.x; idx < 16384; idx += 256) {
        int r = idx >> 7, c = idx & 127;
        float Gcr = Gbase[(size_t)(c * 128 + r) * 16];
        float Grc = Gbase[(size_t)(r * 128 + c) * 16];
        float v = 0.5f * (Gcr - Grc);
        GA[r][c] = v;
        st[r][c] = bf16s(v * 0.125f);
    }
    __syncthreads();
    int lane = threadIdx.x & 63, wave = threadIdx.x >> 6;
    int mh = (wave >> 1) * 64, nh = (wave & 1) * 64;
    int cr = lane & 15, q = lane >> 4;
    s8 afr[4][4];
    #pragma unroll
    for (int mt = 0; mt < 4; mt++) {
        int m = mh + mt * 16 + cr;
        #pragma unroll
        for (int kc = 0; kc < 4; kc++) {
            int k0 = kc * 32 + 8 * q;
            f4 lo = *(const f4*)&GA[m][k0];
            f4 hi = *(const f4*)&GA[m][k0 + 4];
            afr[mt][kc] = pack8(-lo, -hi);
        }
    }
    size_t soff = (size_t)blk * 16384;
    for (int s = 0; s < 7; s++) {
        const float inv = 1.0f / (float)(7 - s);
        f4 acc[4][4] = {};
        #pragma unroll
        for (int nt = 0; nt < 4; nt++) {
            int n = nh + nt * 16 + cr;
            #pragma unroll
            for (int kc = 0; kc < 4; kc++) {
                s8 bfrag = *(const s8*)&st[n][kc * 32 + 8 * q];
                #pragma unroll
                for (int mt = 0; mt < 4; mt++)
                    acc[mt][nt] = mfma_bf16(afr[mt][kc], bfrag, acc[mt][nt]);
            }
        }
        __syncthreads();
        #pragma unroll
        for (int mt = 0; mt < 4; mt++) {
            int m0 = mh + mt * 16 + 4 * q;
            #pragma unroll
            for (int nt = 0; nt < 4; nt++) {
                int n = nh + nt * 16 + cr;
                f4 gv = *(const f4*)&GA[n][m0];
                f4 val = (acc[mt][nt] + gv) * inv;
                if (s < 6) {
                    sh4 w;
                    w[0] = bf16s(val.x); w[1] = bf16s(val.y);
                    w[2] = bf16s(val.z); w[3] = bf16s(val.w);
                    *(sh4*)&st[n][m0] = w;
                } else {
                    *(f4*)(s_tr + soff + (size_t)n * 128 + m0) = val;
                    s_rm[soff + (size_t)(m0 + 0) * 128 + n] = val.x;
                    s_rm[soff + (size_t)(m0 + 1) * 128 + n] = val.y;
                    s_rm[soff + (size_t)(m0 + 2) * 128 + n] = val.z;
                    s_rm[soff + (size_t)(m0 + 3) * 128 + n] = val.w;
                }
            }
        }
        if (s < 6) __syncthreads();
    }
}

__global__ __launch_bounds__(256) void k3b_compose(const float* __restrict__ s_rm,
                                                   const float* __restrict__ s_tr,
                                                   float* __restrict__ sT_rm,
                                                   float* __restrict__ sT_tr,
                                                   short* __restrict__ SRT) {
    int bb = blockIdx.x;
    int lane = threadIdx.x & 63, wave = threadIdx.x >> 6;
    int mh = (wave >> 1) * 64, nh = (wave & 1) * 64;
    int cr = lane & 15, q = lane >> 4;
    const size_t o0 = (size_t)(bb * 3 + 0) * 16384;
    const size_t o1 = (size_t)(bb * 3 + 1) * 16384;
    const size_t o2 = (size_t)(bb * 3 + 2) * 16384;
    const size_t oT = (size_t)bb * 16384;
    {
        s8 afr[4][4];
        #pragma unroll
        for (int mt = 0; mt < 4; mt++) {
            int m = mh + mt * 16 + cr;
            #pragma unroll
            for (int kc = 0; kc < 4; kc++) {
                int k0 = kc * 32 + 8 * q;
                f4 lo = *(const f4*)(s_rm + o0 + (size_t)m * 128 + k0);
                f4 hi = *(const f4*)(s_rm + o0 + (size_t)m * 128 + k0 + 4);
                afr[mt][kc] = pack8(lo, hi);
            }
        }
        f4 acc[4][4] = {};
        #pragma unroll
        for (int nt = 0; nt < 4; nt++) {
            int n = nh + nt * 16 + cr;
            #pragma unroll
            for (int kc = 0; kc < 4; kc++) {
                int k0 = kc * 32 + 8 * q;
                f4 lo = *(const f4*)(s_tr + o1 + (size_t)n * 128 + k0);
                f4 hi = *(const f4*)(s_tr + o1 + (size_t)n * 128 + k0 + 4);
                s8 bfrag = pack8(lo, hi);
                #pragma unroll
                for (int mt = 0; mt < 4; mt++)
                    acc[mt][nt] = mfma_bf16(afr[mt][kc], bfrag, acc[mt][nt]);
            }
        }
        #pragma unroll
        for (int mt = 0; mt < 4; mt++) {
            int m0 = mh + mt * 16 + 4 * q;
            #pragma unroll
            for (int nt = 0; nt < 4; nt++) {
                int n = nh + nt * 16 + cr;
                f4 a = *(const f4*)(s_tr + o0 + (size_t)n * 128 + m0);
                f4 c = *(const f4*)(s_tr + o1 + (size_t)n * 128 + m0);
                f4 val = acc[mt][nt] + a + c;
                *(f4*)(sT_tr + oT + (size_t)n * 128 + m0) = val;
                sT_rm[oT + (size_t)(m0 + 0) * 128 + n] = val.x;
                sT_rm[oT + (size_t)(m0 + 1) * 128 + n] = val.y;
                sT_rm[oT + (size_t)(m0 + 2) * 128 + n] = val.z;
                sT_rm[oT + (size_t)(m0 + 3) * 128 + n] = val.w;
            }
        }
    }
    __syncthreads();
    {
        s8 afr[4][4];
        #pragma unroll
        for (int mt = 0; mt < 4; mt++) {
            int m = mh + mt * 16 + cr;
            #pragma unroll
            for (int kc = 0; kc < 4; kc++) {
                int k0 = kc * 32 + 8 * q;
                f4 lo = *(const f4*)(sT_rm + oT + (size_t)m * 128 + k0);
                f4 hi = *(const f4*)(sT_rm + oT + (size_t)m * 128 + k0 + 4);
                afr[mt][kc] = pack8(lo, hi);
            }
        }
        f4 acc[4][4] = {};
        #pragma unroll
        for (int nt = 0; nt < 4; nt++) {
            int n = nh + nt * 16 + cr;
            #pragma unroll
            for (int kc = 0; kc < 4; kc++) {
                int k0 = kc * 32 + 8 * q;
                f4 lo = *(const f4*)(s_tr + o2 + (size_t)n * 128 + k0);
                f4 hi = *(const f4*)(s_tr + o2 + (size_t)n * 128 + k0 + 4);
                s8 bfrag = pack8(lo, hi);
                #pragma unroll
                for (int mt = 0; mt < 4; mt++)
                    acc[mt][nt] = mfma_bf16(afr[mt][kc], bfrag, acc[mt][nt]);
            }
        }
        #pragma unroll
        for (int mt = 0; mt < 4; mt++) {
            int m0 = mh + mt * 16 + 4 * q;
            #pragma unroll
            for (int nt = 0; nt < 4; nt++) {
                int n = nh + nt * 16 + cr;
                f4 a = *(const f4*)(sT_tr + oT + (size_t)n * 128 + m0);
                f4 c = *(const f4*)(s_tr + o2 + (size_t)n * 128 + m0);
                f4 val = acc[mt][nt] + a + c;
                sh4 w;
                w[0] = bf16s(val.x); w[1] = bf16s(val.y);
                w[2] = bf16s(val.z); w[3] = bf16s(val.w);
                *(sh4*)(SRT + oT + (size_t)n * 128 + m0) = w;
            }
        }
    }
}

__global__ __launch_bounds__(256) void k4_apply(const float* __restrict__ x,
                                                const short* __restrict__ SRT,
                                                float* __restrict__ out) {
    __shared__ float x32[64][132];
    __shared__ short xb[64][136];
    int blk = blockIdx.x;
    int b = blk >> 7, tile = blk & 127;
    const float* xbase = x + ((size_t)b * 8192 + (size_t)tile * 64) * 128;
    float* obase = out + ((size_t)b * 8192 + (size_t)tile * 64) * 128;
    #pragma unroll
    for (int ii = 0; ii < 8; ii++) {
        int flat4 = ii * 256 + threadIdx.x;
        int row = flat4 >> 5, col = (flat4 & 31) * 4;
        f4 v = *(const f4*)(xbase + (size_t)row * 128 + col);
        *(f4*)&x32[row][col] = v;
        sh4 w;
        w[0] = bf16s(v.x); w[1] = bf16s(v.y); w[2] = bf16s(v.z); w[3] = bf16s(v.w);
        *(sh4*)&xb[row][col] = w;
    }
    int lane = threadIdx.x & 63, wave = threadIdx.x >> 6;
    int cr = lane & 15, q = lane >> 4;
    const short* Ab = SRT + (size_t)b * 16384;
    s8 afr[2][4];
    #pragma unroll
    for (int mt = 0; mt < 2; mt++) {
        int e = wave * 32 + mt * 16 + cr;
        #pragma unroll
        for (int kc = 0; kc < 4; kc++)
            afr[mt][kc] = *(const s8*)(Ab + (size_t)e * 128 + kc * 32 + 8 * q);
    }
    __syncthreads();
    #pragma unroll
    for (int strip = 0; strip < 4; strip++) {
        int srow = strip * 16 + cr;
        f4 acc0 = {0.f,0.f,0.f,0.f}, acc1 = {0.f,0.f,0.f,0.f};
        #pragma unroll
        for (int kc = 0; kc < 4; kc++) {
            s8 bfrag = *(const s8*)&xb[srow][kc * 32 + 8 * q];
            acc0 = mfma_bf16(afr[0][kc], bfrag, acc0);
            acc1 = mfma_bf16(afr[1][kc], bfrag, acc1);
        }
        #pragma unroll
        for (int mt = 0; mt < 2; mt++) {
            int e0 = wave * 32 + mt * 16 + 4 * q;
            f4 xv = *(const f4*)&x32[srow][e0];
            f4 o = (mt ? acc1 : acc0) + xv;
            *(f4*)(obase + (size_t)srow * 128 + e0) = o;
        }
    }
}

// ================================ launch ================================
extern "C" void kernel_launch(void* const* d_in, const int* in_sizes, int n_in,
                              void* d_out, int out_size, void* d_ws, size_t ws_size,
                              hipStream_t stream) {
    const float* x  = (const float*)d_in[0];
    const float* W1 = (const float*)d_in[1];
    const float* b1 = (const float*)d_in[2];
    const float* W2 = (const float*)d_in[3];
    const float* b2 = (const float*)d_in[4];
    float* out = (float*)d_out;
    float* ws = (float*)d_ws;

    float* PART  = ws;                     // 1024*128  = 131072
    float* H     = ws + 131072;            // 16*512    = 8192
    float* GT    = ws + 139264;            // 49152*16  = 786432
    float* GGA   = ws + 925696;            // 48*16384  = 786432
    float* S_RM  = ws + 1712128;           // 48*16384  = 786432
    float* S_TR  = ws + 2498560;           // 48*16384  = 786432
    float* ST_RM = ws + 3284992;           // 16*16384  = 262144
    float* ST_TR = ws + 3547136;           // 16*16384  = 262144
    short* SRT   = (short*)(ws + 3809280); // 16*16384 bf16

    int maxB = 0;
    hipError_t oe = hipOccupancyMaxActiveBlocksPerMultiprocessor(&maxB, mega, 256, 0);
    bool coop_ok = (oe == hipSuccess && maxB >= 1);
    if (coop_ok) {
        int grid = maxB * 256;             // 256 CUs on MI355X
        if (grid > 2048) grid = 2048;
        if (grid < 64) grid = 64;
        void* args[] = {(void*)&x, (void*)&W1, (void*)&b1, (void*)&W2, (void*)&b2,
                        (void*)&out, (void*)&PART, (void*)&H, (void*)&GT, (void*)&GGA,
                        (void*)&S_RM, (void*)&S_TR, (void*)&ST_RM, (void*)&ST_TR,
                        (void*)&SRT};
        hipError_t le = hipLaunchCooperativeKernel(mega, dim3(grid), dim3(256),
                                                   args, 0, stream);
        if (le == hipSuccess) return;
    }
    // Fallback: proven 6-kernel pipeline
    hipLaunchKernelGGL(k1_pool,     dim3(1024), dim3(256), 0, stream, x, PART);
    hipLaunchKernelGGL(k2a_h,       dim3(16),   dim3(512), 0, stream, PART, W1, b1, H);
    hipLaunchKernelGGL(k2b_G,       dim3(768),  dim3(256), 0, stream, H, W2, b2, GT);
    hipLaunchKernelGGL(k3_expm,     dim3(48),   dim3(256), 0, stream, GT, S_RM, S_TR);
    hipLaunchKernelGGL(k3b_compose, dim3(16),   dim3(256), 0, stream, S_RM, S_TR, ST_RM, ST_TR, SRT);
    hipLaunchKernelGGL(k4_apply,    dim3(2048), dim3(256), 0, stream, x, SRT, out);
}